// Round 3
// baseline (13962.325 us; speedup 1.0000x reference)
//
#include <hip/hip_runtime.h>
#include <hip/hip_bf16.h>

// Stacked 2-layer Elman RNN, B=2048 T=256 H=512 OUT=1.
// Weight-stationary persistent RNN: 128 blocks x 16 waves; the 3 weight
// matrices (fp16, MFMA-B fragment layout) live in VGPRs, distributed across
// the 16 waves of each block with zero replication (384 VGPR/wave).
// Fragments are PINNED with opaque asm so the compiler cannot sink the
// loads back into the t-loop (round-2 failure: VGPR_Count=64, 22GB refetch).
//   waves 0-7  ("L0"): Wh0 strips, n-tiles 4g..4g+3   (256 VGPR)
//   waves 8-15 ("L1"): Wh1 strips, n-tiles 4g..4g+3   (256 VGPR)
//   all waves:         Wx1 strips, n-tiles 2w..2w+1   (128 VGPR)
// Step: [A] L0: acc=h0@Wh0 -> h0_new || L1: pacc=h1@Wh1 -> LDS.
//       barrier. [B] all: acc2 = pacc + h0_new@Wx1 -> h1_new. barrier(top).

typedef _Float16 half8 __attribute__((ext_vector_type(8)));
typedef float f32x4 __attribute__((ext_vector_type(4)));

#define T_STEPS 256
#define H_DIM   512
#define BM      16

__device__ __forceinline__ void pin(half8 &v){ asm volatile("" : "+v"(v)); }

__device__ __forceinline__ float tanh_fast(float z){
  float az = fabsf(z);
  float e  = __expf(-2.0f * az);
  float r  = (1.0f - e) * __builtin_amdgcn_rcpf(1.0f + e);
  return copysignf(r, z);
}

// fp32 [k][n] -> fp16 MFMA-B fragments: out[(nt*16+kc)*64+lane] = 8 halves,
// col = nt*16 + (lane&15), k = kc*32 + (lane>>4)*8 + j
__global__ void prep_w_45028437131357(const float* __restrict__ W,
                                      half8* __restrict__ out){
  int tid  = blockIdx.x * 256 + threadIdx.x;
  int lane = tid & 63;
  int kc   = (tid >> 6) & 15;
  int nt   = tid >> 10;
  int col  = nt * 16 + (lane & 15);
  int k0   = kc * 32 + (lane >> 4) * 8;
  half8 v;
#pragma unroll
  for (int j = 0; j < 8; ++j) v[j] = (_Float16)W[(k0 + j) * H_DIM + col];
  out[tid] = v;
}

// LDS h layout: element (row, c) at byte  row*1024 + ((c*2) ^ ((row&7)<<4))

__global__ __launch_bounds__(1024, 1)
void rnn_main_45028437131357(const float* __restrict__ x,
                             const float* __restrict__ Wx0,
                             const float* __restrict__ bx0,
                             const float* __restrict__ bh0,
                             const float* __restrict__ bx1,
                             const float* __restrict__ bh1,
                             const float* __restrict__ Wfc,
                             const float* __restrict__ bfc,
                             const half8* __restrict__ Wh0f,
                             const half8* __restrict__ Wx1f,
                             const half8* __restrict__ Wh1f,
                             float* __restrict__ out){
  __shared__ __align__(16) char  h0raw[2][BM * 1024];
  __shared__ __align__(16) char  h1raw[BM * 1024];
  __shared__ __align__(16) float pacc[32 * 64 * 4];   // [tile][lane][4] f32
  __shared__ float xl[BM];

  const int tid  = threadIdx.x;
  const int lane = tid & 63;
  const int wave = tid >> 6;          // 0..15
  const int g    = wave & 7;
  const bool isL0 = (wave < 8);
  const int r0   = blockIdx.x * BM;

  // zero initial hidden state (h0 both buffers + h1)
  for (int i = tid; i < 2 * BM * 256; i += 1024) ((float*)h0raw)[i] = 0.0f;
  for (int i = tid; i < BM * 256;     i += 1024) ((float*)h1raw)[i] = 0.0f;

  // ---- persistent weights -> VGPRs (once), pinned ----
  const half8* wAsrc = isL0 ? Wh0f : Wh1f;
  half8 wA[4][16];
#pragma unroll
  for (int i = 0; i < 4; ++i)
#pragma unroll
    for (int kc = 0; kc < 16; ++kc){
      wA[i][kc] = wAsrc[((4 * g + i) * 16 + kc) * 64 + lane];
      pin(wA[i][kc]);
    }
  half8 wX[2][16];
#pragma unroll
  for (int i = 0; i < 2; ++i)
#pragma unroll
    for (int kc = 0; kc < 16; ++kc){
      wX[i][kc] = Wx1f[((2 * wave + i) * 16 + kc) * 64 + lane];
      pin(wX[i][kc]);
    }

  const int cl      = lane & 15;
  const int kg      = lane >> 4;
  const int aBase   = cl * 1024 + kg * 16;
  const int aSwz    = (cl & 7) << 4;
  const int rowBase = kg * 4;

  // per-column constants
  float wx0c[4], b0c[4];
  int   colA[4];
#pragma unroll
  for (int i = 0; i < 4; ++i){
    int col = (4 * g + i) * 16 + cl;
    colA[i] = col;
    wx0c[i] = Wx0[col];
    b0c[i]  = bx0[col] + bh0[col];
  }
  float b1c[2];
  int   colX[2];
#pragma unroll
  for (int i = 0; i < 2; ++i){
    int col = (2 * wave + i) * 16 + cl;
    colX[i] = col;
    b1c[i]  = bx1[col] + bh1[col];
  }

  float xreg = 0.0f;
  if (tid < BM) xreg = x[(r0 + tid) * T_STEPS];

  const f32x4 z4 = {0.f, 0.f, 0.f, 0.f};
  int s = 0;

  for (int t = 0; t < T_STEPS; ++t){
    if (tid < BM) xl[tid] = xreg;
    __syncthreads();                          // B0: h1_new(t-1), xl visible
    {
      int tn = (t + 1 < T_STEPS) ? t + 1 : t;
      if (tid < BM) xreg = x[(r0 + tid) * T_STEPS + tn];
    }

    // ---- phase A: L0: h0_old@Wh0 ; L1: h1_old@Wh1 ----
    const char* aBuf = isL0 ? h0raw[s] : h1raw;
    f32x4 accA[4] = {z4, z4, z4, z4};
#pragma unroll
    for (int kc = 0; kc < 16; ++kc){
      half8 a = *(const half8*)(aBuf + ((aBase + kc * 64) ^ aSwz));
#pragma unroll
      for (int i = 0; i < 4; ++i)
        accA[i] = __builtin_amdgcn_mfma_f32_16x16x32_f16(a, wA[i][kc], accA[i], 0, 0, 0);
    }

    if (isL0){
      float xv[4];
#pragma unroll
      for (int rg = 0; rg < 4; ++rg) xv[rg] = xl[rowBase + rg];
#pragma unroll
      for (int i = 0; i < 4; ++i)
#pragma unroll
        for (int rg = 0; rg < 4; ++rg){
          float z = accA[i][rg] + b0c[i] + xv[rg] * wx0c[i];
          int row = rowBase + rg;
          *(_Float16*)(h0raw[s ^ 1] + row * 1024 +
                       ((colA[i] * 2) ^ ((row & 7) << 4))) = (_Float16)tanh_fast(z);
        }
    } else {
#pragma unroll
      for (int i = 0; i < 4; ++i)
        *(f32x4*)(pacc + ((4 * g + i) * 64 + lane) * 4) = accA[i];
    }
    __syncthreads();                          // B1: h0_new + pacc visible

    // ---- phase B: all waves: acc2 = pacc + h0_new@Wx1 ----
    f32x4 acc2[2];
#pragma unroll
    for (int i = 0; i < 2; ++i)
      acc2[i] = *(const f32x4*)(pacc + ((2 * wave + i) * 64 + lane) * 4);
#pragma unroll
    for (int kc = 0; kc < 16; ++kc){
      half8 a = *(const half8*)(h0raw[s ^ 1] + ((aBase + kc * 64) ^ aSwz));
#pragma unroll
      for (int i = 0; i < 2; ++i)
        acc2[i] = __builtin_amdgcn_mfma_f32_16x16x32_f16(a, wX[i][kc], acc2[i], 0, 0, 0);
    }
#pragma unroll
    for (int i = 0; i < 2; ++i)
#pragma unroll
      for (int rg = 0; rg < 4; ++rg){
        float z = acc2[i][rg] + b1c[i];
        int row = rowBase + rg;
        *(_Float16*)(h1raw + row * 1024 +
                     ((colX[i] * 2) ^ ((row & 7) << 4))) = (_Float16)tanh_fast(z);
      }
    s ^= 1;
  }
  __syncthreads();

  // ---- final FC: out[r] = h1[r,:] . Wfc + bfc ----
  if (tid < 512){
    int r  = tid >> 5;
    int g2 = tid & 31;
    float p = 0.0f;
#pragma unroll
    for (int k2 = 0; k2 < 16; ++k2){
      int c = g2 + 32 * k2;
      float hv = (float)*(const _Float16*)(h1raw + r * 1024 +
                                           ((c * 2) ^ ((r & 7) << 4)));
      p += hv * Wfc[c];
    }
#pragma unroll
    for (int off = 16; off >= 1; off >>= 1) p += __shfl_xor(p, off);
    if (g2 == 0) out[r0 + r] = p + bfc[0];
  }
}

extern "C" void kernel_launch(void* const* d_in, const int* in_sizes, int n_in,
                              void* d_out, int out_size, void* d_ws, size_t ws_size,
                              hipStream_t stream) {
  const float* x   = (const float*)d_in[0];
  const float* Wx0 = (const float*)d_in[1];
  const float* bx0 = (const float*)d_in[2];
  const float* Wh0 = (const float*)d_in[3];
  const float* bh0 = (const float*)d_in[4];
  const float* Wx1 = (const float*)d_in[5];
  const float* bx1 = (const float*)d_in[6];
  const float* Wh1 = (const float*)d_in[7];
  const float* bh1 = (const float*)d_in[8];
  const float* Wfc = (const float*)d_in[9];
  const float* bfc = (const float*)d_in[10];

  _Float16* wsH = (_Float16*)d_ws;
  half8* Wh0f = (half8*)(wsH);
  half8* Wx1f = (half8*)(wsH + 262144);
  half8* Wh1f = (half8*)(wsH + 524288);

  prep_w_45028437131357<<<128, 256, 0, stream>>>(Wh0, Wh0f);
  prep_w_45028437131357<<<128, 256, 0, stream>>>(Wx1, Wx1f);
  prep_w_45028437131357<<<128, 256, 0, stream>>>(Wh1, Wh1f);

  rnn_main_45028437131357<<<128, 1024, 0, stream>>>(
      x, Wx0, bx0, bh0, bx1, bh1, Wfc, bfc,
      (const half8*)Wh0f, (const half8*)Wx1f, (const half8*)Wh1f,
      (float*)d_out);
}

// Round 4
// 12649.153 us; speedup vs baseline: 1.1038x; 1.1038x over previous
//
#include <hip/hip_runtime.h>
#include <hip/hip_bf16.h>

// Stacked 2-layer Elman RNN, B=2048 T=256 H=512 OUT=1.
// Weight-stationary persistent RNN: 128 blocks x 16 waves; the 3 weight
// matrices (fp16, MFMA-B fragment layout) live in the AGPR file, distributed
// across the 16 waves of each block with zero replication (384 AGPR/wave).
// Round-3 lesson: "+v" pinning made the weights compete with the loop
// working set in the arch-VGPR class -> allocator spilled them to scratch
// (VGPR=64, 21GB HBM refetch). Fix: pin with "+a" (AGPR class). gfx950 MFMA
// operands are AV-class, so the builtin reads B straight from AGPRs.
//   waves 0-7  ("L0"): Wh0 strips, n-tiles 4g..4g+3   (256 AGPR)
//   waves 8-15 ("L1"): Wh1 strips, n-tiles 4g..4g+3   (256 AGPR)
//   all waves:         Wx1 strips, n-tiles 2w..2w+1   (128 AGPR)
// Step: [A] L0: acc=h0@Wh0 -> h0_new || L1: pacc=h1@Wh1 -> LDS.
//       barrier. [B] all: acc2 = pacc + h0_new@Wx1 -> h1_new. barrier(top).

typedef _Float16 half8 __attribute__((ext_vector_type(8)));
typedef float f32x4 __attribute__((ext_vector_type(4)));

#define T_STEPS 256
#define H_DIM   512
#define BM      16

// Pin a loaded fragment into the AGPR register class. The value becomes an
// opaque asm output (cannot be rematerialized from memory) AND lives in the
// AGPR file, out of the way of the loop's arch-VGPR working set.
__device__ __forceinline__ void pinA(half8 &v){ asm volatile("" : "+a"(v)); }

__device__ __forceinline__ float tanh_fast(float z){
  float az = fabsf(z);
  float e  = __expf(-2.0f * az);
  float r  = (1.0f - e) * __builtin_amdgcn_rcpf(1.0f + e);
  return copysignf(r, z);
}

// fp32 [k][n] -> fp16 MFMA-B fragments: out[(nt*16+kc)*64+lane] = 8 halves,
// col = nt*16 + (lane&15), k = kc*32 + (lane>>4)*8 + j
__global__ void prep_w_45028437131357(const float* __restrict__ W,
                                      half8* __restrict__ out){
  int tid  = blockIdx.x * 256 + threadIdx.x;
  int lane = tid & 63;
  int kc   = (tid >> 6) & 15;
  int nt   = tid >> 10;
  int col  = nt * 16 + (lane & 15);
  int k0   = kc * 32 + (lane >> 4) * 8;
  half8 v;
#pragma unroll
  for (int j = 0; j < 8; ++j) v[j] = (_Float16)W[(k0 + j) * H_DIM + col];
  out[tid] = v;
}

// LDS h layout: element (row, c) at byte  row*1024 + ((c*2) ^ ((row&7)<<4))

__global__ __launch_bounds__(1024, 1)
void rnn_main_45028437131357(const float* __restrict__ x,
                             const float* __restrict__ Wx0,
                             const float* __restrict__ bx0,
                             const float* __restrict__ bh0,
                             const float* __restrict__ bx1,
                             const float* __restrict__ bh1,
                             const float* __restrict__ Wfc,
                             const float* __restrict__ bfc,
                             const half8* __restrict__ Wh0f,
                             const half8* __restrict__ Wx1f,
                             const half8* __restrict__ Wh1f,
                             float* __restrict__ out){
  __shared__ __align__(16) char  h0raw[2][BM * 1024];
  __shared__ __align__(16) char  h1raw[BM * 1024];
  __shared__ __align__(16) float pacc[32 * 64 * 4];   // [tile][lane][4] f32
  __shared__ float xl[BM];

  const int tid  = threadIdx.x;
  const int lane = tid & 63;
  const int wave = tid >> 6;          // 0..15
  const int g    = wave & 7;
  const bool isL0 = (wave < 8);
  const int r0   = blockIdx.x * BM;

  // zero initial hidden state (h0 both buffers + h1)
  for (int i = tid; i < 2 * BM * 256; i += 1024) ((float*)h0raw)[i] = 0.0f;
  for (int i = tid; i < BM * 256;     i += 1024) ((float*)h1raw)[i] = 0.0f;

  // ---- persistent weights -> AGPRs (once), pinned ----
  const half8* wAsrc = isL0 ? Wh0f : Wh1f;
  half8 wA[4][16];
#pragma unroll
  for (int i = 0; i < 4; ++i)
#pragma unroll
    for (int kc = 0; kc < 16; ++kc){
      wA[i][kc] = wAsrc[((4 * g + i) * 16 + kc) * 64 + lane];
      pinA(wA[i][kc]);
    }
  half8 wX[2][16];
#pragma unroll
  for (int i = 0; i < 2; ++i)
#pragma unroll
    for (int kc = 0; kc < 16; ++kc){
      wX[i][kc] = Wx1f[((2 * wave + i) * 16 + kc) * 64 + lane];
      pinA(wX[i][kc]);
    }

  const int cl      = lane & 15;
  const int kg      = lane >> 4;
  const int aBase   = cl * 1024 + kg * 16;
  const int aSwz    = (cl & 7) << 4;
  const int rowBase = kg * 4;

  // per-column constants
  float wx0c[4], b0c[4];
  int   colA[4];
#pragma unroll
  for (int i = 0; i < 4; ++i){
    int col = (4 * g + i) * 16 + cl;
    colA[i] = col;
    wx0c[i] = Wx0[col];
    b0c[i]  = bx0[col] + bh0[col];
  }
  float b1c[2];
  int   colX[2];
#pragma unroll
  for (int i = 0; i < 2; ++i){
    int col = (2 * wave + i) * 16 + cl;
    colX[i] = col;
    b1c[i]  = bx1[col] + bh1[col];
  }

  float xreg = 0.0f;
  if (tid < BM) xreg = x[(r0 + tid) * T_STEPS];

  const f32x4 z4 = {0.f, 0.f, 0.f, 0.f};
  int s = 0;

  for (int t = 0; t < T_STEPS; ++t){
    if (tid < BM) xl[tid] = xreg;
    __syncthreads();                          // B0: h1_new(t-1), xl visible
    {
      int tn = (t + 1 < T_STEPS) ? t + 1 : t;
      if (tid < BM) xreg = x[(r0 + tid) * T_STEPS + tn];
    }

    // ---- phase A: L0: h0_old@Wh0 ; L1: h1_old@Wh1 ----
    const char* aBuf = isL0 ? h0raw[s] : h1raw;
    f32x4 accA[4] = {z4, z4, z4, z4};
#pragma unroll
    for (int kc = 0; kc < 16; ++kc){
      half8 a = *(const half8*)(aBuf + ((aBase + kc * 64) ^ aSwz));
#pragma unroll
      for (int i = 0; i < 4; ++i)
        accA[i] = __builtin_amdgcn_mfma_f32_16x16x32_f16(a, wA[i][kc], accA[i], 0, 0, 0);
    }

    if (isL0){
      float xv[4];
#pragma unroll
      for (int rg = 0; rg < 4; ++rg) xv[rg] = xl[rowBase + rg];
#pragma unroll
      for (int i = 0; i < 4; ++i)
#pragma unroll
        for (int rg = 0; rg < 4; ++rg){
          float z = accA[i][rg] + b0c[i] + xv[rg] * wx0c[i];
          int row = rowBase + rg;
          *(_Float16*)(h0raw[s ^ 1] + row * 1024 +
                       ((colA[i] * 2) ^ ((row & 7) << 4))) = (_Float16)tanh_fast(z);
        }
    } else {
#pragma unroll
      for (int i = 0; i < 4; ++i)
        *(f32x4*)(pacc + ((4 * g + i) * 64 + lane) * 4) = accA[i];
    }
    __syncthreads();                          // B1: h0_new + pacc visible

    // ---- phase B: all waves: acc2 = pacc + h0_new@Wx1 ----
    f32x4 acc2[2];
#pragma unroll
    for (int i = 0; i < 2; ++i)
      acc2[i] = *(const f32x4*)(pacc + ((2 * wave + i) * 64 + lane) * 4);
#pragma unroll
    for (int kc = 0; kc < 16; ++kc){
      half8 a = *(const half8*)(h0raw[s ^ 1] + ((aBase + kc * 64) ^ aSwz));
#pragma unroll
      for (int i = 0; i < 2; ++i)
        acc2[i] = __builtin_amdgcn_mfma_f32_16x16x32_f16(a, wX[i][kc], acc2[i], 0, 0, 0);
    }
#pragma unroll
    for (int i = 0; i < 2; ++i)
#pragma unroll
      for (int rg = 0; rg < 4; ++rg){
        float z = acc2[i][rg] + b1c[i];
        int row = rowBase + rg;
        *(_Float16*)(h1raw + row * 1024 +
                     ((colX[i] * 2) ^ ((row & 7) << 4))) = (_Float16)tanh_fast(z);
      }
    s ^= 1;
  }
  __syncthreads();

  // ---- final FC: out[r] = h1[r,:] . Wfc + bfc ----
  if (tid < 512){
    int r  = tid >> 5;
    int g2 = tid & 31;
    float p = 0.0f;
#pragma unroll
    for (int k2 = 0; k2 < 16; ++k2){
      int c = g2 + 32 * k2;
      float hv = (float)*(const _Float16*)(h1raw + r * 1024 +
                                           ((c * 2) ^ ((r & 7) << 4)));
      p += hv * Wfc[c];
    }
#pragma unroll
    for (int off = 16; off >= 1; off >>= 1) p += __shfl_xor(p, off);
    if (g2 == 0) out[r0 + r] = p + bfc[0];
  }
}

extern "C" void kernel_launch(void* const* d_in, const int* in_sizes, int n_in,
                              void* d_out, int out_size, void* d_ws, size_t ws_size,
                              hipStream_t stream) {
  const float* x   = (const float*)d_in[0];
  const float* Wx0 = (const float*)d_in[1];
  const float* bx0 = (const float*)d_in[2];
  const float* Wh0 = (const float*)d_in[3];
  const float* bh0 = (const float*)d_in[4];
  const float* Wx1 = (const float*)d_in[5];
  const float* bx1 = (const float*)d_in[6];
  const float* Wh1 = (const float*)d_in[7];
  const float* bh1 = (const float*)d_in[8];
  const float* Wfc = (const float*)d_in[9];
  const float* bfc = (const float*)d_in[10];

  _Float16* wsH = (_Float16*)d_ws;
  half8* Wh0f = (half8*)(wsH);
  half8* Wx1f = (half8*)(wsH + 262144);
  half8* Wh1f = (half8*)(wsH + 524288);

  prep_w_45028437131357<<<128, 256, 0, stream>>>(Wh0, Wh0f);
  prep_w_45028437131357<<<128, 256, 0, stream>>>(Wx1, Wx1f);
  prep_w_45028437131357<<<128, 256, 0, stream>>>(Wh1, Wh1f);

  rnn_main_45028437131357<<<128, 1024, 0, stream>>>(
      x, Wx0, bx0, bh0, bx1, bh1, Wfc, bfc,
      (const half8*)Wh0f, (const half8*)Wx1f, (const half8*)Wh1f,
      (float*)d_out);
}

// Round 5
// 11389.169 us; speedup vs baseline: 1.2259x; 1.1106x over previous
//
#include <hip/hip_runtime.h>
#include <hip/hip_bf16.h>

// Stacked 2-layer Elman RNN, B=2048 T=256 H=512 OUT=1.
// Weight-stationary persistent RNN: 128 blocks x 16 waves; the 3 weight
// matrices (fp16, MFMA-B fragment layout) live in registers, distributed
// across the 16 waves of each block with zero replication (384 regs/wave).
//
// Round-3/4 lesson: a wave has max 256 arch-VGPRs + 256 AGPRs. Pinning all
// 384 regs into ONE class forced spills (WRITE_SIZE ~200MB = spill stores,
// FETCH 22GB = per-step scratch reloads). Fix: split the stationary set —
//   wA (Wh0 or Wh1 strip, 4x16 frags = 256 regs) -> AGPR  ("+a" pin)
//   wX (Wx1 strip,        2x16 frags = 128 regs) -> VGPR  ("+v" pin)
// VGPR class: 128 pinned + ~70 working set ~= 200 <= 256. Feasible -> no
// forced spill. gfx950 MFMA B-operand is AV-class: AGPR feeds mfma directly.
//
//   waves 0-7  ("L0"): Wh0 strips, n-tiles 4g..4g+3
//   waves 8-15 ("L1"): Wh1 strips, n-tiles 4g..4g+3
//   all waves:         Wx1 strips, n-tiles 2w..2w+1
// Step: [A] L0: acc=h0@Wh0 -> h0_new || L1: pacc=h1@Wh1 -> LDS.
//       barrier. [B] all: acc2 = pacc + h0_new@Wx1 -> h1_new. barrier(top).

typedef _Float16 half8 __attribute__((ext_vector_type(8)));
typedef float f32x4 __attribute__((ext_vector_type(4)));

#define T_STEPS 256
#define H_DIM   512
#define BM      16

__device__ __forceinline__ void pinA(half8 &v){ asm volatile("" : "+a"(v)); }
__device__ __forceinline__ void pinV(half8 &v){ asm volatile("" : "+v"(v)); }

__device__ __forceinline__ float tanh_fast(float z){
  float az = fabsf(z);
  float e  = __expf(-2.0f * az);
  float r  = (1.0f - e) * __builtin_amdgcn_rcpf(1.0f + e);
  return copysignf(r, z);
}

// fp32 [k][n] -> fp16 MFMA-B fragments: out[(nt*16+kc)*64+lane] = 8 halves,
// col = nt*16 + (lane&15), k = kc*32 + (lane>>4)*8 + j
__global__ void prep_w_45028437131357(const float* __restrict__ W,
                                      half8* __restrict__ out){
  int tid  = blockIdx.x * 256 + threadIdx.x;
  int lane = tid & 63;
  int kc   = (tid >> 6) & 15;
  int nt   = tid >> 10;
  int col  = nt * 16 + (lane & 15);
  int k0   = kc * 32 + (lane >> 4) * 8;
  half8 v;
#pragma unroll
  for (int j = 0; j < 8; ++j) v[j] = (_Float16)W[(k0 + j) * H_DIM + col];
  out[tid] = v;
}

// LDS h layout: element (row, c) at byte  row*1024 + ((c*2) ^ ((row&7)<<4))

__global__ __launch_bounds__(1024, 1)
void rnn_main_45028437131357(const float* __restrict__ x,
                             const float* __restrict__ Wx0,
                             const float* __restrict__ bx0,
                             const float* __restrict__ bh0,
                             const float* __restrict__ bx1,
                             const float* __restrict__ bh1,
                             const float* __restrict__ Wfc,
                             const float* __restrict__ bfc,
                             const half8* __restrict__ Wh0f,
                             const half8* __restrict__ Wx1f,
                             const half8* __restrict__ Wh1f,
                             float* __restrict__ out){
  __shared__ __align__(16) char  h0raw[2][BM * 1024];
  __shared__ __align__(16) char  h1raw[BM * 1024];
  __shared__ __align__(16) float pacc[32 * 64 * 4];   // [tile][lane][4] f32
  __shared__ float xl[BM];

  const int tid  = threadIdx.x;
  const int lane = tid & 63;
  const int wave = tid >> 6;          // 0..15
  const int g    = wave & 7;
  const bool isL0 = (wave < 8);
  const int r0   = blockIdx.x * BM;

  // zero initial hidden state (h0 both buffers + h1)
  for (int i = tid; i < 2 * BM * 256; i += 1024) ((float*)h0raw)[i] = 0.0f;
  for (int i = tid; i < BM * 256;     i += 1024) ((float*)h1raw)[i] = 0.0f;

  // ---- persistent weights -> registers (once), pinned per class ----
  const half8* wAsrc = isL0 ? Wh0f : Wh1f;
  half8 wA[4][16];                      // 256 regs -> AGPR file (exactly full)
#pragma unroll
  for (int i = 0; i < 4; ++i)
#pragma unroll
    for (int kc = 0; kc < 16; ++kc){
      wA[i][kc] = wAsrc[((4 * g + i) * 16 + kc) * 64 + lane];
      pinA(wA[i][kc]);
    }
  half8 wX[2][16];                      // 128 regs -> VGPR file
#pragma unroll
  for (int i = 0; i < 2; ++i)
#pragma unroll
    for (int kc = 0; kc < 16; ++kc){
      wX[i][kc] = Wx1f[((2 * wave + i) * 16 + kc) * 64 + lane];
      pinV(wX[i][kc]);
    }

  const int cl      = lane & 15;
  const int kg      = lane >> 4;
  const int aBase   = cl * 1024 + kg * 16;
  const int aSwz    = (cl & 7) << 4;
  const int rowBase = kg * 4;

  // per-column constants
  float wx0c[4], b0c[4];
  int   colA[4];
#pragma unroll
  for (int i = 0; i < 4; ++i){
    int col = (4 * g + i) * 16 + cl;
    colA[i] = col;
    wx0c[i] = Wx0[col];
    b0c[i]  = bx0[col] + bh0[col];
  }
  float b1c[2];
  int   colX[2];
#pragma unroll
  for (int i = 0; i < 2; ++i){
    int col = (2 * wave + i) * 16 + cl;
    colX[i] = col;
    b1c[i]  = bx1[col] + bh1[col];
  }

  float xreg = 0.0f;
  if (tid < BM) xreg = x[(r0 + tid) * T_STEPS];

  const f32x4 z4 = {0.f, 0.f, 0.f, 0.f};
  int s = 0;

  for (int t = 0; t < T_STEPS; ++t){
    if (tid < BM) xl[tid] = xreg;
    __syncthreads();                          // B0: h1_new(t-1), xl visible
    {
      int tn = (t + 1 < T_STEPS) ? t + 1 : t;
      if (tid < BM) xreg = x[(r0 + tid) * T_STEPS + tn];
    }

    // ---- phase A: L0: h0_old@Wh0 ; L1: h1_old@Wh1 ----
    const char* aBuf = isL0 ? h0raw[s] : h1raw;
    f32x4 accA[4] = {z4, z4, z4, z4};
#pragma unroll
    for (int kc = 0; kc < 16; ++kc){
      half8 a = *(const half8*)(aBuf + ((aBase + kc * 64) ^ aSwz));
#pragma unroll
      for (int i = 0; i < 4; ++i)
        accA[i] = __builtin_amdgcn_mfma_f32_16x16x32_f16(a, wA[i][kc], accA[i], 0, 0, 0);
    }

    if (isL0){
      float xv[4];
#pragma unroll
      for (int rg = 0; rg < 4; ++rg) xv[rg] = xl[rowBase + rg];
#pragma unroll
      for (int i = 0; i < 4; ++i)
#pragma unroll
        for (int rg = 0; rg < 4; ++rg){
          float z = accA[i][rg] + b0c[i] + xv[rg] * wx0c[i];
          int row = rowBase + rg;
          *(_Float16*)(h0raw[s ^ 1] + row * 1024 +
                       ((colA[i] * 2) ^ ((row & 7) << 4))) = (_Float16)tanh_fast(z);
        }
    } else {
#pragma unroll
      for (int i = 0; i < 4; ++i)
        *(f32x4*)(pacc + ((4 * g + i) * 64 + lane) * 4) = accA[i];
    }
    __syncthreads();                          // B1: h0_new + pacc visible

    // ---- phase B: all waves: acc2 = pacc + h0_new@Wx1 ----
    f32x4 acc2[2];
#pragma unroll
    for (int i = 0; i < 2; ++i)
      acc2[i] = *(const f32x4*)(pacc + ((2 * wave + i) * 64 + lane) * 4);
#pragma unroll
    for (int kc = 0; kc < 16; ++kc){
      half8 a = *(const half8*)(h0raw[s ^ 1] + ((aBase + kc * 64) ^ aSwz));
#pragma unroll
      for (int i = 0; i < 2; ++i)
        acc2[i] = __builtin_amdgcn_mfma_f32_16x16x32_f16(a, wX[i][kc], acc2[i], 0, 0, 0);
    }
#pragma unroll
    for (int i = 0; i < 2; ++i)
#pragma unroll
      for (int rg = 0; rg < 4; ++rg){
        float z = acc2[i][rg] + b1c[i];
        int row = rowBase + rg;
        *(_Float16*)(h1raw + row * 1024 +
                     ((colX[i] * 2) ^ ((row & 7) << 4))) = (_Float16)tanh_fast(z);
      }
    s ^= 1;
  }
  __syncthreads();

  // ---- final FC: out[r] = h1[r,:] . Wfc + bfc ----
  if (tid < 512){
    int r  = tid >> 5;
    int g2 = tid & 31;
    float p = 0.0f;
#pragma unroll
    for (int k2 = 0; k2 < 16; ++k2){
      int c = g2 + 32 * k2;
      float hv = (float)*(const _Float16*)(h1raw + r * 1024 +
                                           ((c * 2) ^ ((r & 7) << 4)));
      p += hv * Wfc[c];
    }
#pragma unroll
    for (int off = 16; off >= 1; off >>= 1) p += __shfl_xor(p, off);
    if (g2 == 0) out[r0 + r] = p + bfc[0];
  }
}

extern "C" void kernel_launch(void* const* d_in, const int* in_sizes, int n_in,
                              void* d_out, int out_size, void* d_ws, size_t ws_size,
                              hipStream_t stream) {
  const float* x   = (const float*)d_in[0];
  const float* Wx0 = (const float*)d_in[1];
  const float* bx0 = (const float*)d_in[2];
  const float* Wh0 = (const float*)d_in[3];
  const float* bh0 = (const float*)d_in[4];
  const float* Wx1 = (const float*)d_in[5];
  const float* bx1 = (const float*)d_in[6];
  const float* Wh1 = (const float*)d_in[7];
  const float* bh1 = (const float*)d_in[8];
  const float* Wfc = (const float*)d_in[9];
  const float* bfc = (const float*)d_in[10];

  _Float16* wsH = (_Float16*)d_ws;
  half8* Wh0f = (half8*)(wsH);
  half8* Wx1f = (half8*)(wsH + 262144);
  half8* Wh1f = (half8*)(wsH + 524288);

  prep_w_45028437131357<<<128, 256, 0, stream>>>(Wh0, Wh0f);
  prep_w_45028437131357<<<128, 256, 0, stream>>>(Wx1, Wx1f);
  prep_w_45028437131357<<<128, 256, 0, stream>>>(Wh1, Wh1f);

  rnn_main_45028437131357<<<128, 1024, 0, stream>>>(
      x, Wx0, bx0, bh0, bx1, bh1, Wfc, bfc,
      (const half8*)Wh0f, (const half8*)Wx1f, (const half8*)Wh1f,
      (float*)d_out);
}